// Round 25
// baseline (243.957 us; speedup 1.0000x reference)
//
#include <hip/hip_runtime.h>
#include <hip/hip_bf16.h>

#define NTOK 8192
#define SCC  16
#define CD   128
#define WD   512
#define OD   1024
#define ED   640   // WD + CD
#define TW   4     // tokens per scan workgroup
#define LOG2E 1.4426950408889634f

typedef __attribute__((ext_vector_type(8))) short short8;
typedef __attribute__((ext_vector_type(4))) float f32x4;

#if defined(__has_builtin)
#  if __has_builtin(__builtin_amdgcn_exp2f)
#    define EXP2(x) __builtin_amdgcn_exp2f(x)
#  else
#    define EXP2(x) exp2f(x)
#  endif
#else
#  define EXP2(x) exp2f(x)
#endif

__device__ __forceinline__ unsigned short f2bf(float f) {
    union { float f; unsigned u; } v; v.f = f;
    unsigned r = v.u + 0x7FFF + ((v.u >> 16) & 1);   // RNE
    return (unsigned short)(r >> 16);
}

__device__ __forceinline__ unsigned short f2bf_fast(float f) {
    unsigned r;
    asm("v_cvt_pk_bf16_f32 %0, %1, %2" : "=v"(r) : "v"(f), "v"(f));
    return (unsigned short)r;
}

// ---------------------------------------------------------------------------
// Kernel 0 (fully fused prologue), 385 blocks x 256 threads:
//   blocks 0..63   : pack Wg/Wp -> scan B-fragments (Wg pre-scaled by log2 e)
//   blocks 64..383 : pack W_out -> out B-fragments
//   block  384     : counting sort (4 waves). Stable order = (LPT bin,
//                    ascending token idx) — identical permutation to the
//                    1024-thread version (chunk->wave->lane order == idx asc),
//                    so the validated grouping is preserved bit-for-bit.
// ---------------------------------------------------------------------------
__global__ __launch_bounds__(256) void prologue(
    const float* __restrict__ Wg, const float* __restrict__ Wp,
    const float* __restrict__ W_out, const int* __restrict__ lengths,
    uint4* __restrict__ packed, uint4* __restrict__ pwout,
    int* __restrict__ order)
{
    const int blk = blockIdx.x;
    if (blk < 64) {
        const int gid  = blk * 256 + threadIdx.x;  // 0..16383
        const int lane = gid & 63;
        const int kf   = (gid >> 6) & 7;
        const int c    = (gid >> 9) & 3;
        const int w    = (gid >> 11) & 7;
        const int n    = c * 128 + w * 16 + (lane & 15);
        const int k0   = kf * 32 + (lane >> 4) * 8;
        const float sc = (n < 384) ? LOG2E : 1.0f;
        const float* src = (n < 384) ? (Wg + n * 256 + k0) : (Wp + (n - 384) * 256 + k0);
        uint4 o;
        o.x = f2bf(src[0] * sc) | ((unsigned)f2bf(src[1] * sc) << 16);
        o.y = f2bf(src[2] * sc) | ((unsigned)f2bf(src[3] * sc) << 16);
        o.z = f2bf(src[4] * sc) | ((unsigned)f2bf(src[5] * sc) << 16);
        o.w = f2bf(src[6] * sc) | ((unsigned)f2bf(src[7] * sc) << 16);
        packed[gid] = o;
    } else if (blk < 384) {
        const int gid  = (blk - 64) * 256 + threadIdx.x;  // 0..81919
        const int lane = gid & 63;
        const int kf   = (gid >> 6) % 20;
        const int nb   = (gid >> 6) / 20;
        const int n    = nb * 16 + (lane & 15);
        const int k0   = kf * 32 + (lane >> 4) * 8;
        const float* src = W_out + (size_t)n * ED + k0;
        uint4 o;
        o.x = f2bf(src[0]) | ((unsigned)f2bf(src[1]) << 16);
        o.y = f2bf(src[2]) | ((unsigned)f2bf(src[3]) << 16);
        o.z = f2bf(src[4]) | ((unsigned)f2bf(src[5]) << 16);
        o.w = f2bf(src[6]) | ((unsigned)f2bf(src[7]) << 16);
        pwout[gid] = o;
    } else {
        // ---- deterministic stable LPT counting sort, 4 waves ----
        __shared__ int hist[16], base[16], running[16];
        __shared__ int wcnt[4][16];   // [wave][bin]

        const int tid  = threadIdx.x;
        const int lane = tid & 63;
        const int wv   = tid >> 6;    // wave 0..3

        if (tid < 16) hist[tid] = 0;
        __syncthreads();
        for (int i = tid; i < NTOK; i += 256)
            atomicAdd(&hist[lengths[i] - 1], 1);
        __syncthreads();
        if (tid == 0) {
            int acc = 0;
            for (int b = 15; b >= 0; --b) { base[b] = acc; acc += hist[b]; }  // LPT
        }
        if (tid < 16) running[tid] = 0;
        __syncthreads();

        for (int c0 = 0; c0 < NTOK; c0 += 256) {
            const int i     = c0 + tid;
            const int mybin = lengths[i] - 1;
            unsigned long long mymask = 0ull;
#pragma unroll
            for (int b = 0; b < 16; ++b) {
                const unsigned long long mb = __ballot(mybin == b);
                if (lane == 0) wcnt[wv][b] = __popcll(mb);
                if (b == mybin) mymask = mb;
            }
            const int lanerank = __popcll(mymask & ((1ull << lane) - 1ull));
            __syncthreads();
            int pos = base[mybin] + running[mybin] + lanerank;
            for (int w2 = 0; w2 < wv; ++w2) pos += wcnt[w2][mybin];
            order[pos] = i;
            __syncthreads();
            if (tid < 16) {
                int tot = 0;
#pragma unroll
                for (int w2 = 0; w2 < 4; ++w2) tot += wcnt[w2][tid];
                running[tid] += tot;
            }
            __syncthreads();
        }
    }
}

// ---------------------------------------------------------------------------
// Kernel 1: MFMA gated pyramid scan — R19 build (proven 192 us floor over
// ten structural variants R13-R22).
// TW=4 LPT-sorted tokens/WG, 8 waves; double-buffered X, 1 barrier/step;
// kf0,1 pinned; kf2-4 LDS stash; kf5-7 streamed; base-2 gates; cvt_pk.
// ---------------------------------------------------------------------------
#define LOAD_B(DST, KF)                                                     \
    {                                                                       \
        const uint4* wp_ = Wpacked + (w * 32 + (KF)) * 64 + lane;           \
        union { uint4 u; short8 s; } cv0, cv1, cv2, cv3;                    \
        cv0.u = wp_[0];    DST[0] = cv0.s;                                  \
        cv1.u = wp_[512];  DST[1] = cv1.s;                                  \
        cv2.u = wp_[1024]; DST[2] = cv2.s;                                  \
        cv3.u = wp_[1536]; DST[3] = cv3.s;                                  \
    }

#define LOAD_B_LDS(DST, KFI)                                                \
    {                                                                       \
        const uint4* sp_ = SW + ((w * 3 + (KFI)) * 4) * 64 + lane;          \
        union { uint4 u; short8 s; } d0, d1, d2, d3;                        \
        d0.u = sp_[0];   DST[0] = d0.s;                                     \
        d1.u = sp_[64];  DST[1] = d1.s;                                     \
        d2.u = sp_[128]; DST[2] = d2.s;                                     \
        d3.u = sp_[192]; DST[3] = d3.s;                                     \
    }

#define MFMA_PHASE(BV, KF)                                                  \
    {                                                                       \
        _Pragma("unroll")                                                   \
        for (int m_ = 0; m_ < 4; ++m_) {                                    \
            if (m_ < mfrags) {                                              \
                const int r_ = m_ * 16 + col + (((KF) >= 4) ? 4 : 0);       \
                int ba_ = (r_ << 8) + (((KF) & 3) << 6) + (q << 4);         \
                ba_ ^= (r_ & 15) << 4;                                      \
                const short8 a_ = *reinterpret_cast<const short8*>(Xc + ba_); \
                acc[m_][0] = __builtin_amdgcn_mfma_f32_16x16x32_bf16(a_, BV[0], acc[m_][0], 0, 0, 0); \
                acc[m_][1] = __builtin_amdgcn_mfma_f32_16x16x32_bf16(a_, BV[1], acc[m_][1], 0, 0, 0); \
                acc[m_][2] = __builtin_amdgcn_mfma_f32_16x16x32_bf16(a_, BV[2], acc[m_][2], 0, 0, 0); \
                acc[m_][3] = __builtin_amdgcn_mfma_f32_16x16x32_bf16(a_, BV[3], acc[m_][3], 0, 0, 0); \
            }                                                               \
        }                                                                   \
    }

__global__ __launch_bounds__(512, 2) void scan_mfma(
    const int*   __restrict__ char_ids,
    const int*   __restrict__ char_lengths,
    const float* __restrict__ char_table,
    const float* __restrict__ bg, const float* __restrict__ bp,
    const uint4* __restrict__ Wpacked,
    const int*   __restrict__ order,
    unsigned short* __restrict__ char_repr)
{
    __shared__ __align__(16) unsigned short X[2 * 68 * 128];  // 34 KB dbuf state
    __shared__ __align__(16) uint4 SW[8 * 3 * 4 * 64];        // 96 KB kf=2,3,4 stash
    __shared__ int toksh[TW];
    __shared__ int Lsh[TW];

    const int tid  = threadIdx.x;
    const int lane = tid & 63;
    const int w    = tid >> 6;         // wave 0..7
    const int col  = lane & 15;
    const int q    = lane >> 4;        // 0..3

    if (tid < TW) {
        const int tok = order[blockIdx.x * TW + tid];
        toksh[tid] = tok;
        Lsh[tid]   = char_lengths[tok];
    }

    const int dj = w * 16 + col;
    const float b02 = (bg[dj] - bg[256 + dj]) * LOG2E;   // base-2 gate biases
    const float b12 = (bg[128 + dj] - bg[256 + dj]) * LOG2E;
    const float bz  = bp[dj];

    // pinned kf=0,1 weight fragments (step-invariant, loaded once)
    short8 bpin0[4], bpin1[4];
    LOAD_B(bpin0, 0);
    LOAD_B(bpin1, 1);

    // fill the LDS stash: this wave's kf=2,3,4 slices
#pragma unroll
    for (int kfi = 0; kfi < 3; ++kfi)
#pragma unroll
        for (int c = 0; c < 4; ++c)
            SW[((w * 3 + kfi) * 4 + c) * 64 + lane] =
                Wpacked[(w * 32 + c * 8 + (2 + kfi)) * 64 + lane];

    __syncthreads();   // toksh/Lsh + stash ready

    int L[TW];
#pragma unroll
    for (int i = 0; i < TW; ++i) L[i] = Lsh[i];
    const int maxL = max(max(L[0], L[1]), max(L[2], L[3]));

    // init register state: stv[m][i] = char_table[ids[tok[i]][p]][dj], p=m*4+q
    float stv[4][4];
#pragma unroll
    for (int m = 0; m < 4; ++m) {
        const int p = m * 4 + q;
#pragma unroll
        for (int i = 0; i < 4; ++i) {
            const int id = char_ids[toksh[i] * SCC + p];
            stv[m][i] = char_table[id * CD + dj];
        }
    }

    // init BOTH buffers: rows 0..63 from stv; rows 64..67 zero
#pragma unroll
    for (int xb = 0; xb < 2; ++xb) {
        char* Xb = reinterpret_cast<char*>(X) + xb * 17408;
#pragma unroll
        for (int m = 0; m < 4; ++m)
#pragma unroll
            for (int i = 0; i < 4; ++i) {
                const int rl = m * 16 + q * 4 + i;
                int bl = (rl << 8) + (dj << 1);
                bl ^= (rl & 15) << 4;
                *reinterpret_cast<unsigned short*>(Xb + bl) = f2bf_fast(stv[m][i]);
            }
    }
    for (int i2 = tid; i2 < 2 * 4 * 64; i2 += 512) {
        const int xb = i2 >> 8;
        const int r  = 64 + ((i2 >> 6) & 3), ku = i2 & 63;
        int ba = (r << 8) + (ku << 2);
        ba ^= (r & 15) << 4;
        *reinterpret_cast<unsigned*>(reinterpret_cast<char*>(X) + xb * 17408 + ba) = 0u;
    }
    __syncthreads();

    int cur = 0;
    for (int len = 1; len < maxL; ++len) {
        const int Amax   = maxL - len;
        const int mfrags = ((4 * Amax + 15) >> 4);          // read/compute frags
        const int mf_w0  = (Amax + 4) >> 2;                 // ceil((Amax+1)/4)
        const int mf_w   = (mf_w0 < 4) ? mf_w0 : 4;         // write frags

        const char* Xc = reinterpret_cast<const char*>(X) + cur * 17408;
        char*       Xn = reinterpret_cast<char*>(X) + (cur ^ 1) * 17408;

        f32x4 acc[4][4];   // [m-frag][chunk] -> 64 regs (accumulator class)
#pragma unroll
        for (int m = 0; m < 4; ++m)
#pragma unroll
            for (int c = 0; c < 4; ++c) acc[m][c] = (f32x4){0.f, 0.f, 0.f, 0.f};

        // ---- MFMA phase: kf0,1 pinned; kf2-4 from LDS stash; kf5-7 L2 ----
        short8 bA[4], bB[4], bL[4];
        LOAD_B(bA, 5);
        LOAD_B(bB, 6);
        MFMA_PHASE(bpin0, 0);
        LOAD_B_LDS(bL, 0);
        MFMA_PHASE(bpin1, 1);
        MFMA_PHASE(bL, 2);
        LOAD_B_LDS(bL, 1);
        MFMA_PHASE(bL, 3);
        LOAD_B_LDS(bL, 2);
        MFMA_PHASE(bL, 4);
        MFMA_PHASE(bA, 5);
        LOAD_B(bA, 7);
        MFMA_PHASE(bB, 6);
        MFMA_PHASE(bA, 7);

        // ---- combine: all-register; base-2 gates. right via shfl(lane+16) ----
        float shifted[5][4];
#pragma unroll
        for (int m = 0; m < 4; ++m) {
            if (m <= mfrags) {
#pragma unroll
                for (int i = 0; i < 4; ++i)
                    shifted[m][i] = __shfl(stv[m][i], (lane + 16) & 63);
            }
        }
#pragma unroll
        for (int i = 0; i < 4; ++i) shifted[4][i] = 0.f;

#pragma unroll
        for (int m = 0; m < 4; ++m) {
            if (m < mfrags) {
                const int p = m * 4 + q;
#pragma unroll
                for (int i = 0; i < 4; ++i) {
                    const float a0  = acc[m][0][i];
                    const float a1  = acc[m][1][i];
                    const float a2v = acc[m][2][i];
                    const float z   = acc[m][3][i] + bz;
                    const float E0  = EXP2(a0 - a2v + b02);
                    const float E1  = EXP2(a1 - a2v + b12);
                    const float left  = stv[m][i];
                    const float right = (q < 3) ? shifted[m][i] : shifted[m + 1][i];
                    const float inv = __builtin_amdgcn_rcpf(E0 + E1 + 1.0f);
                    const float nv  = (E0 * left + E1 * right + z) * inv;
                    stv[m][i] = (p < L[i] - len) ? nv : stv[m][i];
                }
            }
        }

        // ---- write phase into X[nxt]: frags m < mf_w (covers p=Amax) ----
#pragma unroll
        for (int m = 0; m < 4; ++m) {
            if (m < mf_w) {
#pragma unroll
                for (int i = 0; i < 4; ++i) {
                    const int rl = m * 16 + q * 4 + i;
                    int bl = (rl << 8) + (dj << 1);
                    bl ^= (rl & 15) << 4;
                    *reinterpret_cast<unsigned short*>(Xn + bl) = f2bf_fast(stv[m][i]);
                }
            }
        }
        __syncthreads();   // single barrier: write visibility for next step
        cur ^= 1;
    }

    // char representation = state at p=0 (held by q==0 lanes), stored bf16
    if (q == 0) {
#pragma unroll
        for (int i = 0; i < 4; ++i)
            char_repr[toksh[i] * CD + dj] = f2bf_fast(stv[0][i]);
    }
}

// ---------------------------------------------------------------------------
// Kernel 2: MFMA out-projection — 64-token tiles, 2 WGs per tile (each WG
// computes half the 1024 outputs). Total pwout L2 reads 168 MB.
// ---------------------------------------------------------------------------
#define TPB2 64

__global__ __launch_bounds__(512) void out_mfma(
    const int*   __restrict__ word_inputs,
    const float* __restrict__ word_table,
    const unsigned short* __restrict__ char_repr,   // bf16 bits
    const uint4* __restrict__ pwout,
    const float* __restrict__ b_out,
    float*       __restrict__ out)
{
    __shared__ __align__(16) unsigned short E[TPB2 * ED];   // 80 KB, swizzled

    const int tile = blockIdx.x >> 1;
    const int half = blockIdx.x & 1;
    const int tg   = tile * TPB2;
    const int tid  = threadIdx.x;
    const int lane = tid & 63;
    const int w    = tid >> 6;         // wave 0..7
    const int col  = lane & 15;
    const int q    = lane >> 4;

    // stage word part: 64 tokens x 512 dims as bf16 pairs
    for (int i = tid; i < TPB2 * 256; i += 512) {
        const int rt = i >> 8, kp = i & 255;
        const float2 v = *reinterpret_cast<const float2*>(
            word_table + (size_t)word_inputs[tg + rt] * WD + 2 * kp);
        const unsigned u = f2bf(v.x) | ((unsigned)f2bf(v.y) << 16);
        int baddr = rt * 1280 + kp * 4;
        baddr ^= (rt & 7) << 4;
        *reinterpret_cast<unsigned*>(reinterpret_cast<char*>(E) + baddr) = u;
    }
    // stage char part: 64 tokens x 128 dims (already bf16)
    for (int i = tid; i < TPB2 * 64; i += 512) {
        const int rt = i >> 6, kp = i & 63;
        const unsigned u = *reinterpret_cast<const unsigned*>(
            char_repr + (tg + rt) * CD + 2 * kp);
        int baddr = rt * 1280 + 1024 + kp * 4;
        baddr ^= (rt & 7) << 4;
        *reinterpret_cast<unsigned*>(reinterpret_cast<char*>(E) + baddr) = u;
    }
    __syncthreads();

    f32x4 acc[4][4];   // [m-frag][nf] -> 64 regs
#pragma unroll
    for (int mm = 0; mm < 4; ++mm)
#pragma unroll
        for (int nf = 0; nf < 4; ++nf) acc[mm][nf] = (f32x4){0.f, 0.f, 0.f, 0.f};

    const int nb0 = half * 32 + w * 4;

#pragma unroll 2
    for (int kf = 0; kf < 20; ++kf) {
        short8 a[4];
#pragma unroll
        for (int mm = 0; mm < 4; ++mm) {
            const int row = mm * 16 + col;
            int ba = row * 1280 + kf * 64 + q * 16;
            ba ^= (row & 7) << 4;
            a[mm] = *reinterpret_cast<const short8*>(
                reinterpret_cast<const char*>(E) + ba);
        }
#pragma unroll
        for (int nf = 0; nf < 4; ++nf) {
            union { uint4 u; short8 s; } cv;
            cv.u = pwout[((nb0 + nf) * 20 + kf) * 64 + lane];
#pragma unroll
            for (int mm = 0; mm < 4; ++mm)
                acc[mm][nf] = __builtin_amdgcn_mfma_f32_16x16x32_bf16(
                    a[mm], cv.s, acc[mm][nf], 0, 0, 0);
        }
    }

#pragma unroll
    for (int nf = 0; nf < 4; ++nf) {
        const int j = (nb0 + nf) * 16 + col;
        const float bias = b_out[j];
#pragma unroll
        for (int mm = 0; mm < 4; ++mm)
#pragma unroll
            for (int i = 0; i < 4; ++i) {
                out[(size_t)(tg + mm * 16 + q * 4 + i) * OD + j] = acc[mm][nf][i] + bias;
            }
    }
}

// ---------------------------------------------------------------------------

extern "C" void kernel_launch(void* const* d_in, const int* in_sizes, int n_in,
                              void* d_out, int out_size, void* d_ws, size_t ws_size,
                              hipStream_t stream)
{
    const int*   word_inputs  = (const int*)  d_in[0];
    const int*   char_ids     = (const int*)  d_in[1];
    const int*   char_lengths = (const int*)  d_in[2];
    const float* word_table   = (const float*)d_in[3];
    const float* char_table   = (const float*)d_in[4];
    const float* Wg           = (const float*)d_in[5];
    const float* bg           = (const float*)d_in[6];
    const float* Wp           = (const float*)d_in[7];
    const float* bp           = (const float*)d_in[8];
    const float* W_out        = (const float*)d_in[9];
    const float* b_out        = (const float*)d_in[10];

    float* out = (float*)d_out;
    char* ws = (char*)d_ws;
    unsigned short* char_repr = (unsigned short*)ws;                 // 2 MB bf16
    uint4* Wpacked = (uint4*)(ws + 2 * 1024 * 1024);                 // 256 KB
    int*   order   = (int*)(ws + 2 * 1024 * 1024 + 256 * 1024);      // 32 KB
    uint4* pwout   = (uint4*)(ws + 2 * 1024 * 1024 + 256 * 1024 + 64 * 1024); // 1.3 MB

    prologue<<<385, 256, 0, stream>>>(Wg, Wp, W_out, char_lengths,
                                      Wpacked, pwout, order);
    scan_mfma<<<NTOK / TW, 512, 0, stream>>>(char_ids, char_lengths, char_table,
                                             bg, bp, Wpacked, order, char_repr);
    out_mfma<<<(NTOK / TPB2) * 2, 512, 0, stream>>>(word_inputs, word_table, char_repr,
                                                    pwout, b_out, out);
}

// Round 26
// 219.741 us; speedup vs baseline: 1.1102x; 1.1102x over previous
//
#include <hip/hip_runtime.h>
#include <hip/hip_bf16.h>

#define NTOK 8192
#define SCC  16
#define CD   128
#define WD   512
#define OD   1024
#define ED   640   // WD + CD
#define TW   4     // tokens per scan workgroup
#define LOG2E 1.4426950408889634f

typedef __attribute__((ext_vector_type(8))) short short8;
typedef __attribute__((ext_vector_type(4))) float f32x4;

#if defined(__has_builtin)
#  if __has_builtin(__builtin_amdgcn_exp2f)
#    define EXP2(x) __builtin_amdgcn_exp2f(x)
#  else
#    define EXP2(x) exp2f(x)
#  endif
#else
#  define EXP2(x) exp2f(x)
#endif

__device__ __forceinline__ unsigned short f2bf(float f) {
    union { float f; unsigned u; } v; v.f = f;
    unsigned r = v.u + 0x7FFF + ((v.u >> 16) & 1);   // RNE
    return (unsigned short)(r >> 16);
}

__device__ __forceinline__ unsigned short f2bf_fast(float f) {
    unsigned r;
    asm("v_cvt_pk_bf16_f32 %0, %1, %2" : "=v"(r) : "v"(f), "v"(f));
    return (unsigned short)r;
}

// ---------------------------------------------------------------------------
// Kernel 0 (fused prologue), 97 blocks x 1024 threads:
//   blocks 0..15  : pack Wg/Wp -> scan B-fragments (Wg pre-scaled by log2 e)
//   blocks 16..95 : pack W_out -> out B-fragments
//   block  96     : counting sort at FULL 1024-thread parallelism — exactly
//                   R24's validated sort_all (identical permutation).
// R25 lesson: fusing at 256 threads starved the sort (4x slower) and the
// whole prologue waited on it. 1024 threads keeps sort speed AND one launch.
// ---------------------------------------------------------------------------
__global__ __launch_bounds__(1024) void prologue(
    const float* __restrict__ Wg, const float* __restrict__ Wp,
    const float* __restrict__ W_out, const int* __restrict__ lengths,
    uint4* __restrict__ packed, uint4* __restrict__ pwout,
    int* __restrict__ order)
{
    const int blk = blockIdx.x;
    if (blk < 16) {
        const int gid  = blk * 1024 + threadIdx.x;  // 0..16383
        const int lane = gid & 63;
        const int kf   = (gid >> 6) & 7;
        const int c    = (gid >> 9) & 3;
        const int w    = (gid >> 11) & 7;
        const int n    = c * 128 + w * 16 + (lane & 15);
        const int k0   = kf * 32 + (lane >> 4) * 8;
        const float sc = (n < 384) ? LOG2E : 1.0f;
        const float* src = (n < 384) ? (Wg + n * 256 + k0) : (Wp + (n - 384) * 256 + k0);
        uint4 o;
        o.x = f2bf(src[0] * sc) | ((unsigned)f2bf(src[1] * sc) << 16);
        o.y = f2bf(src[2] * sc) | ((unsigned)f2bf(src[3] * sc) << 16);
        o.z = f2bf(src[4] * sc) | ((unsigned)f2bf(src[5] * sc) << 16);
        o.w = f2bf(src[6] * sc) | ((unsigned)f2bf(src[7] * sc) << 16);
        packed[gid] = o;
    } else if (blk < 96) {
        const int gid  = (blk - 16) * 1024 + threadIdx.x;  // 0..81919
        const int lane = gid & 63;
        const int kf   = (gid >> 6) % 20;
        const int nb   = (gid >> 6) / 20;
        const int n    = nb * 16 + (lane & 15);
        const int k0   = kf * 32 + (lane >> 4) * 8;
        const float* src = W_out + (size_t)n * ED + k0;
        uint4 o;
        o.x = f2bf(src[0]) | ((unsigned)f2bf(src[1]) << 16);
        o.y = f2bf(src[2]) | ((unsigned)f2bf(src[3]) << 16);
        o.z = f2bf(src[4]) | ((unsigned)f2bf(src[5]) << 16);
        o.w = f2bf(src[6]) | ((unsigned)f2bf(src[7]) << 16);
        pwout[gid] = o;
    } else {
        // ---- deterministic stable LPT counting sort, 16 waves (R24 exact) ----
        __shared__ int hist[16], base[16], running[16];
        __shared__ int wcnt[16][16];   // [wave][bin]

        const int tid  = threadIdx.x;
        const int lane = tid & 63;
        const int wv   = tid >> 6;     // wave 0..15

        if (tid < 16) hist[tid] = 0;
        __syncthreads();
        for (int i = tid; i < NTOK; i += 1024)
            atomicAdd(&hist[lengths[i] - 1], 1);
        __syncthreads();
        if (tid == 0) {
            int acc = 0;
            for (int b = 15; b >= 0; --b) { base[b] = acc; acc += hist[b]; }  // LPT
        }
        if (tid < 16) running[tid] = 0;
        __syncthreads();

        for (int c0 = 0; c0 < NTOK; c0 += 1024) {
            const int i     = c0 + tid;
            const int mybin = lengths[i] - 1;
            unsigned long long mymask = 0ull;
#pragma unroll
            for (int b = 0; b < 16; ++b) {
                const unsigned long long mb = __ballot(mybin == b);
                if (lane == 0) wcnt[wv][b] = __popcll(mb);
                if (b == mybin) mymask = mb;
            }
            const int lanerank = __popcll(mymask & ((1ull << lane) - 1ull));
            __syncthreads();
            int pos = base[mybin] + running[mybin] + lanerank;
            for (int w2 = 0; w2 < wv; ++w2) pos += wcnt[w2][mybin];
            order[pos] = i;
            __syncthreads();
            if (tid < 16) {
                int tot = 0;
#pragma unroll
                for (int w2 = 0; w2 < 16; ++w2) tot += wcnt[w2][tid];
                running[tid] += tot;
            }
            __syncthreads();
        }
    }
}

// ---------------------------------------------------------------------------
// Kernel 1: MFMA gated pyramid scan — R19 build (proven 192 us floor over
// ten structural variants R13-R22).
// TW=4 LPT-sorted tokens/WG, 8 waves; double-buffered X, 1 barrier/step;
// kf0,1 pinned; kf2-4 LDS stash; kf5-7 streamed; base-2 gates; cvt_pk.
// ---------------------------------------------------------------------------
#define LOAD_B(DST, KF)                                                     \
    {                                                                       \
        const uint4* wp_ = Wpacked + (w * 32 + (KF)) * 64 + lane;           \
        union { uint4 u; short8 s; } cv0, cv1, cv2, cv3;                    \
        cv0.u = wp_[0];    DST[0] = cv0.s;                                  \
        cv1.u = wp_[512];  DST[1] = cv1.s;                                  \
        cv2.u = wp_[1024]; DST[2] = cv2.s;                                  \
        cv3.u = wp_[1536]; DST[3] = cv3.s;                                  \
    }

#define LOAD_B_LDS(DST, KFI)                                                \
    {                                                                       \
        const uint4* sp_ = SW + ((w * 3 + (KFI)) * 4) * 64 + lane;          \
        union { uint4 u; short8 s; } d0, d1, d2, d3;                        \
        d0.u = sp_[0];   DST[0] = d0.s;                                     \
        d1.u = sp_[64];  DST[1] = d1.s;                                     \
        d2.u = sp_[128]; DST[2] = d2.s;                                     \
        d3.u = sp_[192]; DST[3] = d3.s;                                     \
    }

#define MFMA_PHASE(BV, KF)                                                  \
    {                                                                       \
        _Pragma("unroll")                                                   \
        for (int m_ = 0; m_ < 4; ++m_) {                                    \
            if (m_ < mfrags) {                                              \
                const int r_ = m_ * 16 + col + (((KF) >= 4) ? 4 : 0);       \
                int ba_ = (r_ << 8) + (((KF) & 3) << 6) + (q << 4);         \
                ba_ ^= (r_ & 15) << 4;                                      \
                const short8 a_ = *reinterpret_cast<const short8*>(Xc + ba_); \
                acc[m_][0] = __builtin_amdgcn_mfma_f32_16x16x32_bf16(a_, BV[0], acc[m_][0], 0, 0, 0); \
                acc[m_][1] = __builtin_amdgcn_mfma_f32_16x16x32_bf16(a_, BV[1], acc[m_][1], 0, 0, 0); \
                acc[m_][2] = __builtin_amdgcn_mfma_f32_16x16x32_bf16(a_, BV[2], acc[m_][2], 0, 0, 0); \
                acc[m_][3] = __builtin_amdgcn_mfma_f32_16x16x32_bf16(a_, BV[3], acc[m_][3], 0, 0, 0); \
            }                                                               \
        }                                                                   \
    }

__global__ __launch_bounds__(512, 2) void scan_mfma(
    const int*   __restrict__ char_ids,
    const int*   __restrict__ char_lengths,
    const float* __restrict__ char_table,
    const float* __restrict__ bg, const float* __restrict__ bp,
    const uint4* __restrict__ Wpacked,
    const int*   __restrict__ order,
    unsigned short* __restrict__ char_repr)
{
    __shared__ __align__(16) unsigned short X[2 * 68 * 128];  // 34 KB dbuf state
    __shared__ __align__(16) uint4 SW[8 * 3 * 4 * 64];        // 96 KB kf=2,3,4 stash
    __shared__ int toksh[TW];
    __shared__ int Lsh[TW];

    const int tid  = threadIdx.x;
    const int lane = tid & 63;
    const int w    = tid >> 6;         // wave 0..7
    const int col  = lane & 15;
    const int q    = lane >> 4;        // 0..3

    if (tid < TW) {
        const int tok = order[blockIdx.x * TW + tid];
        toksh[tid] = tok;
        Lsh[tid]   = char_lengths[tok];
    }

    const int dj = w * 16 + col;
    const float b02 = (bg[dj] - bg[256 + dj]) * LOG2E;   // base-2 gate biases
    const float b12 = (bg[128 + dj] - bg[256 + dj]) * LOG2E;
    const float bz  = bp[dj];

    // pinned kf=0,1 weight fragments (step-invariant, loaded once)
    short8 bpin0[4], bpin1[4];
    LOAD_B(bpin0, 0);
    LOAD_B(bpin1, 1);

    // fill the LDS stash: this wave's kf=2,3,4 slices
#pragma unroll
    for (int kfi = 0; kfi < 3; ++kfi)
#pragma unroll
        for (int c = 0; c < 4; ++c)
            SW[((w * 3 + kfi) * 4 + c) * 64 + lane] =
                Wpacked[(w * 32 + c * 8 + (2 + kfi)) * 64 + lane];

    __syncthreads();   // toksh/Lsh + stash ready

    int L[TW];
#pragma unroll
    for (int i = 0; i < TW; ++i) L[i] = Lsh[i];
    const int maxL = max(max(L[0], L[1]), max(L[2], L[3]));

    // init register state: stv[m][i] = char_table[ids[tok[i]][p]][dj], p=m*4+q
    float stv[4][4];
#pragma unroll
    for (int m = 0; m < 4; ++m) {
        const int p = m * 4 + q;
#pragma unroll
        for (int i = 0; i < 4; ++i) {
            const int id = char_ids[toksh[i] * SCC + p];
            stv[m][i] = char_table[id * CD + dj];
        }
    }

    // init BOTH buffers: rows 0..63 from stv; rows 64..67 zero
#pragma unroll
    for (int xb = 0; xb < 2; ++xb) {
        char* Xb = reinterpret_cast<char*>(X) + xb * 17408;
#pragma unroll
        for (int m = 0; m < 4; ++m)
#pragma unroll
            for (int i = 0; i < 4; ++i) {
                const int rl = m * 16 + q * 4 + i;
                int bl = (rl << 8) + (dj << 1);
                bl ^= (rl & 15) << 4;
                *reinterpret_cast<unsigned short*>(Xb + bl) = f2bf_fast(stv[m][i]);
            }
    }
    for (int i2 = tid; i2 < 2 * 4 * 64; i2 += 512) {
        const int xb = i2 >> 8;
        const int r  = 64 + ((i2 >> 6) & 3), ku = i2 & 63;
        int ba = (r << 8) + (ku << 2);
        ba ^= (r & 15) << 4;
        *reinterpret_cast<unsigned*>(reinterpret_cast<char*>(X) + xb * 17408 + ba) = 0u;
    }
    __syncthreads();

    int cur = 0;
    for (int len = 1; len < maxL; ++len) {
        const int Amax   = maxL - len;
        const int mfrags = ((4 * Amax + 15) >> 4);          // read/compute frags
        const int mf_w0  = (Amax + 4) >> 2;                 // ceil((Amax+1)/4)
        const int mf_w   = (mf_w0 < 4) ? mf_w0 : 4;         // write frags

        const char* Xc = reinterpret_cast<const char*>(X) + cur * 17408;
        char*       Xn = reinterpret_cast<char*>(X) + (cur ^ 1) * 17408;

        f32x4 acc[4][4];   // [m-frag][chunk] -> 64 regs (accumulator class)
#pragma unroll
        for (int m = 0; m < 4; ++m)
#pragma unroll
            for (int c = 0; c < 4; ++c) acc[m][c] = (f32x4){0.f, 0.f, 0.f, 0.f};

        // ---- MFMA phase: kf0,1 pinned; kf2-4 from LDS stash; kf5-7 L2 ----
        short8 bA[4], bB[4], bL[4];
        LOAD_B(bA, 5);
        LOAD_B(bB, 6);
        MFMA_PHASE(bpin0, 0);
        LOAD_B_LDS(bL, 0);
        MFMA_PHASE(bpin1, 1);
        MFMA_PHASE(bL, 2);
        LOAD_B_LDS(bL, 1);
        MFMA_PHASE(bL, 3);
        LOAD_B_LDS(bL, 2);
        MFMA_PHASE(bL, 4);
        MFMA_PHASE(bA, 5);
        LOAD_B(bA, 7);
        MFMA_PHASE(bB, 6);
        MFMA_PHASE(bA, 7);

        // ---- combine: all-register; base-2 gates. right via shfl(lane+16) ----
        float shifted[5][4];
#pragma unroll
        for (int m = 0; m < 4; ++m) {
            if (m <= mfrags) {
#pragma unroll
                for (int i = 0; i < 4; ++i)
                    shifted[m][i] = __shfl(stv[m][i], (lane + 16) & 63);
            }
        }
#pragma unroll
        for (int i = 0; i < 4; ++i) shifted[4][i] = 0.f;

#pragma unroll
        for (int m = 0; m < 4; ++m) {
            if (m < mfrags) {
                const int p = m * 4 + q;
#pragma unroll
                for (int i = 0; i < 4; ++i) {
                    const float a0  = acc[m][0][i];
                    const float a1  = acc[m][1][i];
                    const float a2v = acc[m][2][i];
                    const float z   = acc[m][3][i] + bz;
                    const float E0  = EXP2(a0 - a2v + b02);
                    const float E1  = EXP2(a1 - a2v + b12);
                    const float left  = stv[m][i];
                    const float right = (q < 3) ? shifted[m][i] : shifted[m + 1][i];
                    const float inv = __builtin_amdgcn_rcpf(E0 + E1 + 1.0f);
                    const float nv  = (E0 * left + E1 * right + z) * inv;
                    stv[m][i] = (p < L[i] - len) ? nv : stv[m][i];
                }
            }
        }

        // ---- write phase into X[nxt]: frags m < mf_w (covers p=Amax) ----
#pragma unroll
        for (int m = 0; m < 4; ++m) {
            if (m < mf_w) {
#pragma unroll
                for (int i = 0; i < 4; ++i) {
                    const int rl = m * 16 + q * 4 + i;
                    int bl = (rl << 8) + (dj << 1);
                    bl ^= (rl & 15) << 4;
                    *reinterpret_cast<unsigned short*>(Xn + bl) = f2bf_fast(stv[m][i]);
                }
            }
        }
        __syncthreads();   // single barrier: write visibility for next step
        cur ^= 1;
    }

    // char representation = state at p=0 (held by q==0 lanes), stored bf16
    if (q == 0) {
#pragma unroll
        for (int i = 0; i < 4; ++i)
            char_repr[toksh[i] * CD + dj] = f2bf_fast(stv[0][i]);
    }
}

// ---------------------------------------------------------------------------
// Kernel 2: MFMA out-projection — 64-token tiles, 2 WGs per tile (each WG
// computes half the 1024 outputs). Total pwout L2 reads 168 MB.
// ---------------------------------------------------------------------------
#define TPB2 64

__global__ __launch_bounds__(512) void out_mfma(
    const int*   __restrict__ word_inputs,
    const float* __restrict__ word_table,
    const unsigned short* __restrict__ char_repr,   // bf16 bits
    const uint4* __restrict__ pwout,
    const float* __restrict__ b_out,
    float*       __restrict__ out)
{
    __shared__ __align__(16) unsigned short E[TPB2 * ED];   // 80 KB, swizzled

    const int tile = blockIdx.x >> 1;
    const int half = blockIdx.x & 1;
    const int tg   = tile * TPB2;
    const int tid  = threadIdx.x;
    const int lane = tid & 63;
    const int w    = tid >> 6;         // wave 0..7
    const int col  = lane & 15;
    const int q    = lane >> 4;

    // stage word part: 64 tokens x 512 dims as bf16 pairs
    for (int i = tid; i < TPB2 * 256; i += 512) {
        const int rt = i >> 8, kp = i & 255;
        const float2 v = *reinterpret_cast<const float2*>(
            word_table + (size_t)word_inputs[tg + rt] * WD + 2 * kp);
        const unsigned u = f2bf(v.x) | ((unsigned)f2bf(v.y) << 16);
        int baddr = rt * 1280 + kp * 4;
        baddr ^= (rt & 7) << 4;
        *reinterpret_cast<unsigned*>(reinterpret_cast<char*>(E) + baddr) = u;
    }
    // stage char part: 64 tokens x 128 dims (already bf16)
    for (int i = tid; i < TPB2 * 64; i += 512) {
        const int rt = i >> 6, kp = i & 63;
        const unsigned u = *reinterpret_cast<const unsigned*>(
            char_repr + (tg + rt) * CD + 2 * kp);
        int baddr = rt * 1280 + 1024 + kp * 4;
        baddr ^= (rt & 7) << 4;
        *reinterpret_cast<unsigned*>(reinterpret_cast<char*>(E) + baddr) = u;
    }
    __syncthreads();

    f32x4 acc[4][4];   // [m-frag][nf] -> 64 regs
#pragma unroll
    for (int mm = 0; mm < 4; ++mm)
#pragma unroll
        for (int nf = 0; nf < 4; ++nf) acc[mm][nf] = (f32x4){0.f, 0.f, 0.f, 0.f};

    const int nb0 = half * 32 + w * 4;

#pragma unroll 2
    for (int kf = 0; kf < 20; ++kf) {
        short8 a[4];
#pragma unroll
        for (int mm = 0; mm < 4; ++mm) {
            const int row = mm * 16 + col;
            int ba = row * 1280 + kf * 64 + q * 16;
            ba ^= (row & 7) << 4;
            a[mm] = *reinterpret_cast<const short8*>(
                reinterpret_cast<const char*>(E) + ba);
        }
#pragma unroll
        for (int nf = 0; nf < 4; ++nf) {
            union { uint4 u; short8 s; } cv;
            cv.u = pwout[((nb0 + nf) * 20 + kf) * 64 + lane];
#pragma unroll
            for (int mm = 0; mm < 4; ++mm)
                acc[mm][nf] = __builtin_amdgcn_mfma_f32_16x16x32_bf16(
                    a[mm], cv.s, acc[mm][nf], 0, 0, 0);
        }
    }

#pragma unroll
    for (int nf = 0; nf < 4; ++nf) {
        const int j = (nb0 + nf) * 16 + col;
        const float bias = b_out[j];
#pragma unroll
        for (int mm = 0; mm < 4; ++mm)
#pragma unroll
            for (int i = 0; i < 4; ++i) {
                out[(size_t)(tg + mm * 16 + q * 4 + i) * OD + j] = acc[mm][nf][i] + bias;
            }
    }
}

// ---------------------------------------------------------------------------

extern "C" void kernel_launch(void* const* d_in, const int* in_sizes, int n_in,
                              void* d_out, int out_size, void* d_ws, size_t ws_size,
                              hipStream_t stream)
{
    const int*   word_inputs  = (const int*)  d_in[0];
    const int*   char_ids     = (const int*)  d_in[1];
    const int*   char_lengths = (const int*)  d_in[2];
    const float* word_table   = (const float*)d_in[3];
    const float* char_table   = (const float*)d_in[4];
    const float* Wg           = (const float*)d_in[5];
    const float* bg           = (const float*)d_in[6];
    const float* Wp           = (const float*)d_in[7];
    const float* bp           = (const float*)d_in[8];
    const float* W_out        = (const float*)d_in[9];
    const float* b_out        = (const float*)d_in[10];

    float* out = (float*)d_out;
    char* ws = (char*)d_ws;
    unsigned short* char_repr = (unsigned short*)ws;                 // 2 MB bf16
    uint4* Wpacked = (uint4*)(ws + 2 * 1024 * 1024);                 // 256 KB
    int*   order   = (int*)(ws + 2 * 1024 * 1024 + 256 * 1024);      // 32 KB
    uint4* pwout   = (uint4*)(ws + 2 * 1024 * 1024 + 256 * 1024 + 64 * 1024); // 1.3 MB

    prologue<<<97, 1024, 0, stream>>>(Wg, Wp, W_out, char_lengths,
                                      Wpacked, pwout, order);
    scan_mfma<<<NTOK / TW, 512, 0, stream>>>(char_ids, char_lengths, char_table,
                                             bg, bp, Wpacked, order, char_repr);
    out_mfma<<<(NTOK / TPB2) * 2, 512, 0, stream>>>(word_inputs, word_table, char_repr,
                                                    pwout, b_out, out);
}